// Round 9
// baseline (23.693 us; speedup 1.0000x reference)
//
#include <hip/hip_runtime.h>

#define HD 32

typedef __attribute__((ext_vector_type(8))) short bf16x8;
typedef __attribute__((ext_vector_type(4))) float f32x4;

__device__ __forceinline__ int cvtpk_bf16(float a, float b) {
    int r;
    asm("v_cvt_pk_bf16_f32 %0, %1, %2" : "=v"(r) : "v"(a), "v"(b));
    return r;  // [bf16(b) | bf16(a)], a in low half
}

__device__ __forceinline__ void split_pair(float a, float b, int& hi, int& lo) {
    hi = cvtpk_bf16(a, b);
    float fa = __int_as_float(hi << 16);
    float fb = __int_as_float((unsigned)hi & 0xffff0000u);
    lo = cvtpk_bf16(a - fa, b - fb);
}

__device__ __forceinline__ bf16x8 pack4(int w0, int w1, int w2, int w3) {
    union { int i[4]; bf16x8 v; } u;
    u.i[0] = w0; u.i[1] = w1; u.i[2] = w2; u.i[3] = w3;
    return u.v;
}

// W_hh only: f32x4 pair -> split bf16 fragments (hi + residual). The recurrence
// weight MUST keep the residual: r8 proved its rounding error compounds
// multiplicatively through the 168-step recurrence (absmax 1.19 vs 0.0156).
__device__ __forceinline__ void split_frag(f32x4 a, f32x4 b, bf16x8& hi, bf16x8& lo) {
    int h0,h1,h2,h3,l0,l1,l2,l3;
    split_pair(a[0], a[1], h0, l0);
    split_pair(a[2], a[3], h1, l1);
    split_pair(b[0], b[1], h2, l2);
    split_pair(b[2], b[3], h3, l3);
    hi = pack4(h0,h1,h2,h3);
    lo = pack4(l0,l1,l2,l3);
}

__device__ __forceinline__ bf16x8 to_bf16_frag(f32x4 a, f32x4 b) {
    return pack4(cvtpk_bf16(a[0], a[1]), cvtpk_bf16(a[2], a[3]),
                 cvtpk_bf16(b[0], b[1]), cvtpk_bf16(b[2], b[3]));
}

// relu on packed bf16 pair (sign-monotonic 16-bit max vs +0; exact here)
__device__ __forceinline__ int pk_relu(int v) {
    int r;
    asm("v_pk_max_f16 %0, %1, 0" : "=v"(r) : "v"(v));
    return r;
}

// Quad prefetch: SGPR base (time t), lane-constant voffset; two timesteps' pairs.
__device__ __forceinline__ void gload_quad(f32x4& a1, f32x4& b1, f32x4& a2, f32x4& b2,
                                           const float* sbase, int voff) {
    asm volatile("global_load_dwordx4 %0, %4, %5\n\t"
                 "global_load_dwordx4 %1, %4, %5 offset:16\n\t"
                 "global_load_dwordx4 %2, %4, %5 offset:128\n\t"
                 "global_load_dwordx4 %3, %4, %5 offset:144"
                 : "=&v"(a1), "=&v"(b1), "=&v"(a2), "=&v"(b2)
                 : "v"(voff), "s"(sbase));
}

// Counted waits; "+v" ties give consumers true SSA deps on the wait (rule-#18 safe:
// the consumed value is routed THROUGH the wait asm, so it cannot hoist).
#define WAIT_VM8(N,a0,b0,a1,b1,a2,b2,a3,b3) \
    asm volatile("s_waitcnt vmcnt(" #N ")" : "+v"(a0),"+v"(b0),"+v"(a1),"+v"(b1), \
                                             "+v"(a2),"+v"(b2),"+v"(a3),"+v"(b3))
#define WAIT_LGKM2(N, a, b) \
    asm volatile("s_waitcnt lgkmcnt(" #N ")" : "+v"(a), "+v"(b))

// LDS read pair via asm: addr is a raw LDS byte offset (low 32 bits of the
// generic address of a __shared__ pointer == LDS segment offset on AMDGPU).
__device__ __forceinline__ void lds_read_pair(f32x4& a, f32x4& b, unsigned addr) {
    asm volatile("ds_read_b128 %0, %2\n\t"
                 "ds_read_b128 %1, %2 offset:16384"
                 : "=&v"(a), "=&v"(b) : "v"(addr));
}

#define MFMA(a,b,c) __builtin_amdgcn_mfma_f32_16x16x32_bf16((a),(b),(c),0,0,0)

// Producer/consumer: wave B computes xp[t]=W_ih*x+bias 8-12 steps ahead into a
// 16-slot LDS ring; wave A runs only the recurrence chain. Raw s_barrier every
// 4 steps (B drains lgkm only; vmcnt stays in flight across barriers).
// Ring safety: after barrier k, slots for t<4k+8 are written; B writes [4k+8,4k+12);
// A reads/prefetches t <= 4k+5. Slot reuse distance 16 > 12. Barrier counts: 43 == 43.
__global__ __launch_bounds__(128, 1)
void rnn_pc(const float* __restrict__ x,
            const float* __restrict__ h0p,
            const float* __restrict__ W_ih,
            const float* __restrict__ W_hh,
            const float* __restrict__ b_ih,
            const float* __restrict__ b_hh,
            const float* __restrict__ W_out,
            const float* __restrict__ b_out,
            float* __restrict__ out,
            int B, int T)
{
    __shared__ __align__(16) f32x4 smX[2][16][64];   // 32 KB; region 1 at +16384 B

    const int tid = threadIdx.x;
    const int wid = tid >> 6;
    const int l   = tid & 63;
    const int q   = l >> 4;
    const int c   = l & 15;
    const int bglob = blockIdx.x * 16 + c;
    const int rA0 = ((c >> 2) << 3) + (c & 3);   // permuted A-row (D==next-B trick)
    const int rA1 = rA0 + 4;
    const int NPH2 = T / 8;                       // 21 phase-pairs

    if (wid == 1) {
        // ================= producer (wave B) =================
        bf16x8 Wih0, Wih1;
        {
            const f32x4* p;
            p = (const f32x4*)(W_ih + rA0*HD + q*8); Wih0 = to_bf16_frag(p[0], p[1]);
            p = (const f32x4*)(W_ih + rA1*HD + q*8); Wih1 = to_bf16_frag(p[0], p[1]);
        }
        f32x4 bias0, bias1;
#pragma unroll
        for (int r = 0; r < 4; ++r) {
            bias0[r] = b_ih[q*8 + r]     + b_hh[q*8 + r];
            bias1[r] = b_ih[q*8 + 4 + r] + b_hh[q*8 + 4 + r];
        }
        const int voff = (int)(((size_t)bglob * T * HD + q * 8) * 4);

        f32x4 xa[8], xb[8];
        // prologue: loads t=0..7
        gload_quad(xa[0],xb[0],xa[1],xb[1], x + (size_t)0*HD, voff);
        gload_quad(xa[2],xb[2],xa[3],xb[3], x + (size_t)2*HD, voff);
        gload_quad(xa[4],xb[4],xa[5],xb[5], x + (size_t)4*HD, voff);
        gload_quad(xa[6],xb[6],xa[7],xb[7], x + (size_t)6*HD, voff);
        // produce xp[0..3]
        WAIT_VM8(8, xa[0],xb[0],xa[1],xb[1],xa[2],xb[2],xa[3],xb[3]);
#pragma unroll
        for (int i = 0; i < 4; ++i) {
            bf16x8 xbf = to_bf16_frag(xa[i], xb[i]);
            smX[0][i][l] = MFMA(Wih0, xbf, bias0);
            smX[1][i][l] = MFMA(Wih1, xbf, bias1);
        }
        // produce xp[4..7]
        WAIT_VM8(0, xa[4],xb[4],xa[5],xb[5],xa[6],xb[6],xa[7],xb[7]);
#pragma unroll
        for (int i = 4; i < 8; ++i) {
            bf16x8 xbf = to_bf16_frag(xa[i], xb[i]);
            smX[0][i][l] = MFMA(Wih0, xbf, bias0);
            smX[1][i][l] = MFMA(Wih1, xbf, bias1);
        }
        // loads t=8..15 into slots 0..7
        gload_quad(xa[0],xb[0],xa[1],xb[1], x + (size_t) 8*HD, voff);
        gload_quad(xa[2],xb[2],xa[3],xb[3], x + (size_t)10*HD, voff);
        gload_quad(xa[4],xb[4],xa[5],xb[5], x + (size_t)12*HD, voff);
        gload_quad(xa[6],xb[6],xa[7],xb[7], x + (size_t)14*HD, voff);
        asm volatile("s_waitcnt lgkmcnt(0)" ::: "memory");
        __builtin_amdgcn_s_barrier();                       // prologue barrier

        for (int p2 = 0; p2 < NPH2; ++p2) {
            // ---- phase E: produce t in [8*p2+8, 8*p2+12), reg slots 0..3 ----
            const int tE = 8*p2 + 8;
            WAIT_VM8(8, xa[0],xb[0],xa[1],xb[1],xa[2],xb[2],xa[3],xb[3]);
#pragma unroll
            for (int i = 0; i < 4; ++i) {
                bf16x8 xbf = to_bf16_frag(xa[i], xb[i]);
                const int sl = (tE + i) & 15;
                smX[0][sl][l] = MFMA(Wih0, xbf, bias0);
                smX[1][sl][l] = MFMA(Wih1, xbf, bias1);
            }
            {
                int t1 = tE + 8;  if (t1 > T-2) t1 = T-2;
                int t2 = tE + 10; if (t2 > T-2) t2 = T-2;
                gload_quad(xa[0],xb[0],xa[1],xb[1], x + (size_t)t1*HD, voff);
                gload_quad(xa[2],xb[2],xa[3],xb[3], x + (size_t)t2*HD, voff);
            }
            asm volatile("s_waitcnt lgkmcnt(0)" ::: "memory");
            __builtin_amdgcn_s_barrier();
            // ---- phase O: produce t in [8*p2+12, 8*p2+16), reg slots 4..7 ----
            const int tO = 8*p2 + 12;
            WAIT_VM8(8, xa[4],xb[4],xa[5],xb[5],xa[6],xb[6],xa[7],xb[7]);
#pragma unroll
            for (int i = 0; i < 4; ++i) {
                bf16x8 xbf = to_bf16_frag(xa[4+i], xb[4+i]);
                const int sl = (tO + i) & 15;
                smX[0][sl][l] = MFMA(Wih0, xbf, bias0);
                smX[1][sl][l] = MFMA(Wih1, xbf, bias1);
            }
            {
                int t1 = tO + 8;  if (t1 > T-2) t1 = T-2;
                int t2 = tO + 10; if (t2 > T-2) t2 = T-2;
                gload_quad(xa[4],xb[4],xa[5],xb[5], x + (size_t)t1*HD, voff);
                gload_quad(xa[6],xb[6],xa[7],xb[7], x + (size_t)t2*HD, voff);
            }
            asm volatile("s_waitcnt lgkmcnt(0)" ::: "memory");
            __builtin_amdgcn_s_barrier();
        }
        // producer exits (barrier count: 1 + 2*NPH2 == consumer's)
    } else {
        // ================= consumer (wave A) =================
        bf16x8 Whh0h, Whh0l, Whh1h, Whh1l;
        {
            const f32x4* p;
            p = (const f32x4*)(W_hh + rA0*HD + q*8); split_frag(p[0], p[1], Whh0h, Whh0l);
            p = (const f32x4*)(W_hh + rA1*HD + q*8); split_frag(p[0], p[1], Whh1h, Whh1l);
        }
        bf16x8 h_bf;
        {
            const f32x4* p = (const f32x4*)(h0p + (size_t)bglob * HD + q * 8);
            h_bf = to_bf16_frag(p[0], p[1]);
        }
        const unsigned lbase = (unsigned)(uintptr_t)&smX[0][0][l];

        f32x4 rdA[4], rdB[4];
        f32x4 hA = {0,0,0,0}, hB = {0,0,0,0};

        __builtin_amdgcn_s_barrier();                       // prologue barrier
        asm volatile("" ::: "memory");
        lds_read_pair(rdA[0], rdB[0], lbase);               // xp[0]
        lds_read_pair(rdA[1], rdB[1], lbase + 1024);        // xp[1]

        const int NPH = 2 * NPH2;                           // 42 phases of 4 steps
        for (int k = 0; k < NPH; ++k) {
            const int t0 = 4 * k;
#pragma unroll
            for (int i = 0; i < 4; ++i) {
                // consume xp[t0+i] (read issued 2 steps ago; 2 newer reads in flight)
                WAIT_LGKM2(2, rdA[i], rdB[i]);
                f32x4 a0 = MFMA(Whh0h, h_bf, rdA[i]);
                f32x4 a1 = MFMA(Whh1h, h_bf, rdB[i]);
                a0 = MFMA(Whh0l, h_bf, a0);
                a1 = MFMA(Whh1l, h_bf, a1);
                // prefetch xp[t0+i+2]
                lds_read_pair(rdA[(i+2)&3], rdB[(i+2)&3],
                              lbase + (unsigned)(((t0 + i + 2) & 15) * 1024));
                // relu + pack: D regs -> next B fragment (permutation trick)
                h_bf = pack4(pk_relu(cvtpk_bf16(a0[0], a0[1])),
                             pk_relu(cvtpk_bf16(a0[2], a0[3])),
                             pk_relu(cvtpk_bf16(a1[0], a1[1])),
                             pk_relu(cvtpk_bf16(a1[2], a1[3])));
                hA = a0; hB = a1;                           // pre-relu f32 of last step
            }
            asm volatile("" ::: "memory");
            __builtin_amdgcn_s_barrier();
            asm volatile("" ::: "memory");
        }

        // epilogue: f32 relu of final step, hT + pred
#pragma unroll
        for (int r = 0; r < 4; ++r) {
            hA[r] = fmaxf(hA[r], 0.0f);
            hB[r] = fmaxf(hB[r], 0.0f);
        }
        float* outh = out + B + (size_t)bglob * HD;
#pragma unroll
        for (int r = 0; r < 4; ++r) {
            outh[q*8 + r]     = hA[r];
            outh[q*8 + 4 + r] = hB[r];
        }
        float p = 0.0f;
#pragma unroll
        for (int r = 0; r < 4; ++r)
            p += hA[r] * W_out[q*8 + r] + hB[r] * W_out[q*8 + 4 + r];
        p += __shfl_xor(p, 16, 64);
        p += __shfl_xor(p, 32, 64);
        if (q == 0) out[bglob] = p + b_out[0];
    }
}

extern "C" void kernel_launch(void* const* d_in, const int* in_sizes, int n_in,
                              void* d_out, int out_size, void* d_ws, size_t ws_size,
                              hipStream_t stream) {
    const float* x      = (const float*)d_in[0];
    const float* hidden = (const float*)d_in[1];
    const float* W_ih   = (const float*)d_in[2];
    const float* W_hh   = (const float*)d_in[3];
    const float* b_ih   = (const float*)d_in[4];
    const float* b_hh   = (const float*)d_in[5];
    const float* W_out  = (const float*)d_in[6];
    const float* b_out  = (const float*)d_in[7];
    float* out = (float*)d_out;

    const int B = in_sizes[1] / HD;          // hidden is (1, B, H)
    const int T = in_sizes[0] / (B * HD);    // x is (B, T, 32); T=168 = 8*21

    rnn_pc<<<dim3(B / 16), dim3(128), 0, stream>>>(
        x, hidden, W_ih, W_hh, b_ih, b_hh, W_out, b_out, out, B, T);
}